// Round 9
// baseline (260.931 us; speedup 1.0000x reference)
//
#include <hip/hip_runtime.h>
#include <math.h>

namespace {
constexpr int W = 256, H = 256, TILE = 16, NTX = 16, NT = 256, K = 256;
constexpr float FX = 200.0f, FY = 200.0f, NEARP = 0.3f, MAGIC = 1.2f;
constexpr float LP = 0.3f / (FX * FX);
constexpr float HALF_W = W * MAGIC / 2.0f / FX;   // 0.768
constexpr float HALF_H = H * MAGIC / 2.0f / FY;   // 0.768
constexpr float THDIAG = 0.05656854249492381f;    // 0.5*sqrt((TILE/FX)^2+(TILE/FY)^2)
constexpr int CAP = 1024;        // cnt ~ 157 +- 12.5
constexpr int N_PAD = 10240;
constexpr int BT = 1024;
constexpr int NB_MAX = 64;
constexpr int SEG = 256;
constexpr int RPT = 16;          // diagnostic repeat factor (per-phase rocprof visibility)
// ws layout
constexpr size_t A_OFF  = 0;                                   // pa: (mx,my,radius,z)
constexpr size_t B_OFF  = A_OFF + (size_t)N_PAD * 16;          // pb: (a,b,c,ivd)
constexpr size_t C_OFF  = B_OFF + (size_t)N_PAD * 16;          // pc: (opa,cr,cg,cb)
constexpr size_t SL_OFF = C_OFF + (size_t)N_PAD * 16;          // seglen[NT*NB_MAX]
constexpr size_t LD_OFF = SL_OFF + (size_t)NT * NB_MAX * 4;    // listd
constexpr size_t LZ_OFF = LD_OFF + (size_t)NT * NB_MAX * SEG * 8;  // listz
constexpr size_t QA_OFF = LZ_OFF + (size_t)NT * NB_MAX * SEG * 8;  // qa: NT*K float4
constexpr size_t QB_OFF = QA_OFF + (size_t)NT * K * 16;            // qb: NT*K float4
constexpr size_t QC_OFF = QB_OFF + (size_t)NT * K * 16;            // qc: NT*K float2
constexpr size_t QN_OFF = QC_OFF + (size_t)NT * K * 8;             // qcnt: NT ints
constexpr size_t WS_FULL = QN_OFF + 1024;
}

struct Pre { float mx, my, z, a, b, c, radius; };

__device__ inline Pre preprocess(int g, const float* __restrict__ pos,
                                 const float* __restrict__ quat,
                                 const float* __restrict__ scl,
                                 const float* __restrict__ w2cr,
                                 const float* __restrict__ w2ct) {
  float p0 = pos[3*g+0], p1 = pos[3*g+1], p2 = pos[3*g+2];
  float qw = quat[4*g+0], qx = quat[4*g+1], qy = quat[4*g+2], qz = quat[4*g+3];
  float inv = 1.0f / sqrtf(qw*qw + qx*qx + qy*qy + qz*qz);
  qw *= inv; qx *= inv; qy *= inv; qz *= inv;
  float r00 = 1.f-2.f*(qy*qy+qz*qz), r01 = 2.f*(qx*qy-qw*qz), r02 = 2.f*(qx*qz+qw*qy);
  float r10 = 2.f*(qx*qy+qw*qz), r11 = 1.f-2.f*(qx*qx+qz*qz), r12 = 2.f*(qy*qz-qw*qx);
  float r20 = 2.f*(qx*qz-qw*qy), r21 = 2.f*(qy*qz+qw*qx), r22 = 1.f-2.f*(qx*qx+qy*qy);
  float e0 = expf(scl[3*g+0]); float s0 = e0*e0;
  float e1 = expf(scl[3*g+1]); float s1 = e1*e1;
  float e2 = expf(scl[3*g+2]); float s2 = e2*e2;
  float C00 = r00*r00*s0 + r01*r01*s1 + r02*r02*s2;
  float C01 = r00*r10*s0 + r01*r11*s1 + r02*r12*s2;
  float C02 = r00*r20*s0 + r01*r21*s1 + r02*r22*s2;
  float C11 = r10*r10*s0 + r11*r11*s1 + r12*r12*s2;
  float C12 = r10*r20*s0 + r11*r21*s1 + r12*r22*s2;
  float C22 = r20*r20*s0 + r21*r21*s1 + r22*r22*s2;
  float w00=w2cr[0],w01=w2cr[1],w02=w2cr[2];
  float w10=w2cr[3],w11=w2cr[4],w12=w2cr[5];
  float w20=w2cr[6],w21=w2cr[7],w22=w2cr[8];
  float x = w00*p0 + w01*p1 + w02*p2 + w2ct[0];
  float y = w10*p0 + w11*p1 + w12*p2 + w2ct[1];
  float z = w20*p0 + w21*p1 + w22*p2 + w2ct[2];
  float m00 = w00*C00 + w01*C01 + w02*C02;
  float m01 = w00*C01 + w01*C11 + w02*C12;
  float m02 = w00*C02 + w01*C12 + w02*C22;
  float m10 = w10*C00 + w11*C01 + w12*C02;
  float m11 = w10*C01 + w11*C11 + w12*C12;
  float m12 = w10*C02 + w11*C12 + w12*C22;
  float m20 = w20*C00 + w21*C01 + w22*C02;
  float m21 = w20*C01 + w21*C11 + w22*C12;
  float m22 = w20*C02 + w21*C12 + w22*C22;
  float v00 = m00*w00 + m01*w01 + m02*w02;
  float v01 = m00*w10 + m01*w11 + m02*w12;
  float v02 = m00*w20 + m01*w21 + m02*w22;
  float v10 = m10*w00 + m11*w01 + m12*w02;
  float v11 = m10*w10 + m11*w11 + m12*w12;
  float v12 = m10*w20 + m11*w21 + m12*w22;
  float v20 = m20*w00 + m21*w01 + m22*w02;
  float v21 = m20*w10 + m21*w11 + m22*w12;
  float v22 = m20*w20 + m21*w21 + m22*w22;
  float zc = fmaxf(z, 1e-6f);
  float iz = 1.0f / zc;
  float mx = x * iz, my = y * iz;
  float iz2 = iz * iz;
  float jx = -x * iz2, jy = -y * iz2;
  float a00 = iz*v00 + jx*v20, a01 = iz*v01 + jx*v21, a02 = iz*v02 + jx*v22;
  float a10 = iz*v10 + jy*v20, a11 = iz*v11 + jy*v21, a12 = iz*v12 + jy*v22;
  float A  = a00*iz + a02*jx + LP;
  float Bv = a01*iz + a02*jy;
  float Cv = a11*iz + a12*jy + LP;
  float mid = 0.5f*(A + Cv);
  float hh  = 0.5f*(A - Cv);
  float disc = fmaxf(hh*hh + Bv*Bv, 0.0f);
  float smax = sqrtf(fmaxf(mid + sqrtf(disc), 1e-12f));
  bool infr = (z > NEARP) && (fabsf(mx) < HALF_W) && (fabsf(my) < HALF_H);
  Pre r;
  r.mx = mx; r.my = my; r.z = z; r.a = A; r.b = Bv; r.c = Cv;
  r.radius = infr ? (3.0f * smax + THDIAG) : -1.0f;
  return r;
}

// ---- phase A (looped): preprocess + segmented binning ----

__global__ __launch_bounds__(256)
void pre_bin_r(const float* __restrict__ pos, const float* __restrict__ rgb,
               const float* __restrict__ opac, const float* __restrict__ quat,
               const float* __restrict__ scl, const float* __restrict__ w2cr,
               const float* __restrict__ w2ct,
               float4* __restrict__ pa, float4* __restrict__ pb,
               float4* __restrict__ pc, int* __restrict__ seglen,
               unsigned long long* __restrict__ listd,
               unsigned long long* __restrict__ listz, int n) {
  __shared__ int s_tc[NT];
  const int tid = (int)threadIdx.x;
  const int blk = (int)blockIdx.x;
  const int g = blk * 256 + tid;
  for (int rep = 0; rep < RPT; ++rep) {
    if (tid < NT) s_tc[tid] = 0;
    __syncthreads();
    if (g < n) {
      Pre p = preprocess(g, pos, quat, scl, w2cr, w2ct);
      float det = fmaxf(p.a * p.c - p.b * p.b, 1e-12f);
      pa[g] = make_float4(p.mx, p.my, p.radius, p.z);
      pb[g] = make_float4(p.a, p.b, p.c, 1.0f / det);
      pc[g] = make_float4(1.0f / (1.0f + __expf(-opac[g])),
                          1.0f / (1.0f + __expf(-rgb[3*g+0])),
                          1.0f / (1.0f + __expf(-rgb[3*g+1])),
                          1.0f / (1.0f + __expf(-rgb[3*g+2])));
      if (p.radius >= 0.0f) {
        float r = p.radius;
        int txlo = max(0,     (int)floorf(((p.mx - r) * FX + 120.0f) * 0.0625f));
        int txhi = min(NTX-1, (int)ceilf (((p.mx + r) * FX + 120.0f) * 0.0625f));
        int tylo = max(0,     (int)floorf(((p.my - r) * FY + 120.0f) * 0.0625f));
        int tyhi = min(NTX-1, (int)ceilf (((p.my + r) * FY + 120.0f) * 0.0625f));
        unsigned long long gbits = (unsigned int)g;
        for (int ty = tylo; ty <= tyhi; ++ty) {
          float cy = (ty * TILE + TILE * 0.5f - H * 0.5f) / FY;
          float ddy = cy - p.my;
          for (int tx = txlo; tx <= txhi; ++tx) {
            float cx = (tx * TILE + TILE * 0.5f - W * 0.5f) / FX;
            float ddx = cx - p.mx;
            float dist = sqrtf(ddx * ddx + ddy * ddy);   // exact reference predicate
            if (dist <= r) {
              int t = ty * NTX + tx;
              int slot = atomicAdd(&s_tc[t], 1);
              size_t idx = ((size_t)t * NB_MAX + blk) * SEG + slot;
              listd[idx] = ((unsigned long long)__float_as_uint(dist) << 32) | gbits;
              listz[idx] = ((unsigned long long)__float_as_uint(p.z)  << 32) | gbits;
            }
          }
        }
      }
    }
    __syncthreads();
    if (tid < NT) seglen[(size_t)tid * NB_MAX + blk] = s_tc[tid];
    __syncthreads();
  }
}

// ---- hybrid bitonic (rare cnt>K path only), M <= 1024, BT threads ----

__device__ inline void hsort1(unsigned long long* key, int M) {
  const int tid = (int)threadIdx.x;
  __syncthreads();
  unsigned long long e = (tid < M) ? key[tid] : ~0ull;
  for (int k = 2; k <= M; k <<= 1) {
    for (int j = k >> 1; j >= 64; j >>= 1) {
      __syncthreads();
      if (tid < M) key[tid] = e;
      __syncthreads();
      if (tid < M) {
        unsigned long long p = key[tid ^ j];
        bool takeMin = (((tid & j) == 0) == ((tid & k) == 0));
        e = ((p < e) == takeMin) ? p : e;   // keys unique
      }
    }
    int j0 = ((k >> 1) < 32) ? (k >> 1) : 32;
    for (int j = j0; j >= 1; j >>= 1) {
      unsigned long long p = __shfl_xor(e, j, 64);
      bool takeMin = (((tid & j) == 0) == ((tid & k) == 0));
      e = ((p < e) == takeMin) ? p : e;
    }
  }
  __syncthreads();
  if (tid < M) key[tid] = e;
  __syncthreads();
}

// ---- phase B (looped): gather -> (topK) -> rank z-sort -> scatter to ws ----

__global__ __launch_bounds__(BT)
void sort_k(const float4* __restrict__ pa, const float4* __restrict__ pb,
            const float4* __restrict__ pc, const int* __restrict__ seglen,
            const unsigned long long* __restrict__ listd,
            const unsigned long long* __restrict__ listz,
            float4* __restrict__ qa, float4* __restrict__ qb,
            float2* __restrict__ qc, int* __restrict__ qcnt, int nb) {
  __shared__ unsigned long long s_zkey[CAP];
  __shared__ unsigned long long s_dkey[CAP];
  __shared__ int s_off[NB_MAX + 1];
  __shared__ int s_rank[K];

  const int t  = (int)blockIdx.x;
  const int tid = (int)threadIdx.x;

  for (int rep = 0; rep < RPT; ++rep) {
    if (tid < K) s_rank[tid] = 0;
    if (tid < 64) {
      int v = (tid < nb) ? seglen[(size_t)t * NB_MAX + tid] : 0;
      #pragma unroll
      for (int d = 1; d < 64; d <<= 1) {
        int u2 = __shfl_up(v, d, 64);
        if (tid >= d) v += u2;
      }
      if (tid == 0) s_off[0] = 0;
      if (tid < nb) s_off[tid + 1] = v;
    }
    __syncthreads();
    int cnt = min(s_off[nb], CAP);

    for (int i = tid; i < cnt; i += BT) {
      int lo = 0, hi = nb;
      while (hi - lo > 1) {
        int mid = (lo + hi) >> 1;
        if (s_off[mid] <= i) lo = mid; else hi = mid;
      }
      size_t src = ((size_t)t * NB_MAX + lo) * SEG + (size_t)(i - s_off[lo]);
      s_zkey[i] = listz[src];
    }
    __syncthreads();
    int cnt2 = cnt;

    if (cnt > K) {
      for (int i = tid; i < cnt; i += BT) {
        int lo = 0, hi = nb;
        while (hi - lo > 1) {
          int mid = (lo + hi) >> 1;
          if (s_off[mid] <= i) lo = mid; else hi = mid;
        }
        size_t src = ((size_t)t * NB_MAX + lo) * SEG + (size_t)(i - s_off[lo]);
        s_dkey[i] = listd[src];
      }
      int M = 512; while (M < cnt) M <<= 1;
      for (int i = cnt + tid; i < M; i += BT) s_dkey[i] = ~0ull;
      hsort1(s_dkey, M);
      if (tid < K) {
        int g = (int)(s_dkey[tid] & 0xffffffffu);
        s_zkey[tid] = ((unsigned long long)__float_as_uint(pa[g].w) << 32) |
                      (unsigned int)g;
      }
      __syncthreads();
      cnt2 = K;
    }

    // rank sort by (z, idx)
    {
      const int e = tid & 255;
      const int q = tid >> 8;
      if (e < cnt2) {
        unsigned long long mykey = s_zkey[e];
        int jlo = q * 64;
        int jhi = min(cnt2, jlo + 64);
        int partial = 0;
        for (int j = jlo; j < jhi; ++j)
          partial += (s_zkey[j] < mykey) ? 1 : 0;
        if (partial) atomicAdd(&s_rank[e], partial);
      }
    }
    __syncthreads();

    // scatter blend-ready params to ws at rank position
    if (tid < cnt2) {
      int g = (int)(s_zkey[tid] & 0xffffffffu);
      int r = s_rank[tid];
      float4 A = pa[g], B = pb[g], C = pc[g];
      qa[(size_t)t * K + r] = make_float4(A.x, A.y, B.x, B.y);   // mx,my,a,b
      qb[(size_t)t * K + r] = make_float4(B.z, B.w, C.x, C.y);   // c,ivd,opa,cr
      qc[(size_t)t * K + r] = make_float2(C.z, C.w);             // cg,cb
    }
    if (tid == 0) qcnt[t] = cnt2;
    __syncthreads();
  }
}

// ---- phase C (looped): coalesced load -> split-k blend -> combine -> store ----

__global__ __launch_bounds__(BT)
void blend_k(const float4* __restrict__ qa, const float4* __restrict__ qb,
             const float2* __restrict__ qc, const int* __restrict__ qcnt,
             float* __restrict__ out) {
  __shared__ float4 s_p0[K];
  __shared__ float4 s_p1[K];
  __shared__ float2 s_p2[K];
  __shared__ float4 s_part[BT];

  const int t  = (int)blockIdx.x;
  const int tx = t % NTX;
  const int ty = t / NTX;
  const int tid = (int)threadIdx.x;
  const int cnt2 = qcnt[t];

  const int p    = tid & 255;
  const int q    = tid >> 8;
  const int prow = p / TILE, pcol = p % TILE;
  const float u = ((float)(tx * TILE + pcol) + 0.5f - W * 0.5f) / FX;
  const float v = ((float)(ty * TILE + prow) + 0.5f - H * 0.5f) / FY;

  for (int rep = 0; rep < RPT; ++rep) {
    if (tid < cnt2) {
      s_p0[tid] = qa[(size_t)t * K + tid];
      s_p1[tid] = qb[(size_t)t * K + tid];
      s_p2[tid] = qc[(size_t)t * K + tid];
    }
    __syncthreads();

    const int chunk = (cnt2 + 3) >> 2;
    const int k0 = q * chunk;
    const int k1 = min(cnt2, k0 + chunk);
    float T = 1.0f, accr = 0.0f, accg = 0.0f, accb = 0.0f;
    for (int k2 = k0; k2 < k1; ++k2) {
      float4 p0 = s_p0[k2];
      float4 p1 = s_p1[k2];
      float2 p2 = s_p2[k2];
      float dx = u - p0.x;
      float dy = v - p0.y;
      float maha = (p1.x*dx*dx - 2.0f*p0.w*dx*dy + p0.z*dy*dy) * p1.y;
      float alpha = fminf(p1.z * __expf(-0.5f * maha), 0.99f);
      float w = alpha * T;
      accr += w * p1.w;
      accg += w * p2.x;
      accb += w * p2.y;
      T *= (1.0f - alpha);
    }
    s_part[tid] = make_float4(accr, accg, accb, T);
    __syncthreads();
    if (q == 0) {
      float4 P0 = s_part[p];
      float4 P1 = s_part[p + 256];
      float4 P2 = s_part[p + 512];
      float4 P3 = s_part[p + 768];
      float r = P0.x + P0.w * (P1.x + P1.w * (P2.x + P2.w * P3.x));
      float g = P0.y + P0.w * (P1.y + P1.w * (P2.y + P2.w * P3.y));
      float b = P0.z + P0.w * (P1.z + P1.w * (P2.z + P2.w * P3.z));
      const int row = ty * TILE + prow;
      const int col = tx * TILE + pcol;
      const int o = (row * W + col) * 3;
      out[o+0] = fminf(fmaxf(r, 0.0f), 1.0f);
      out[o+1] = fminf(fmaxf(g, 0.0f), 1.0f);
      out[o+2] = fminf(fmaxf(b, 0.0f), 1.0f);
    }
    __syncthreads();
  }
}

// ---- fallback: 2-kernel scan path (ws too small) ----

__global__ __launch_bounds__(256)
void pre_only(const float* __restrict__ pos, const float* __restrict__ rgb,
              const float* __restrict__ opac, const float* __restrict__ quat,
              const float* __restrict__ scl, const float* __restrict__ w2cr,
              const float* __restrict__ w2ct,
              float4* __restrict__ pa, float4* __restrict__ pb,
              float4* __restrict__ pc, int n) {
  int g = blockIdx.x * 256 + (int)threadIdx.x;
  if (g >= n) return;
  Pre p = preprocess(g, pos, quat, scl, w2cr, w2ct);
  float det = fmaxf(p.a * p.c - p.b * p.b, 1e-12f);
  pa[g] = make_float4(p.mx, p.my, p.radius, p.z);
  pb[g] = make_float4(p.a, p.b, p.c, 1.0f / det);
  pc[g] = make_float4(1.0f / (1.0f + __expf(-opac[g])),
                      1.0f / (1.0f + __expf(-rgb[3*g+0])),
                      1.0f / (1.0f + __expf(-rgb[3*g+1])),
                      1.0f / (1.0f + __expf(-rgb[3*g+2])));
}

__global__ __launch_bounds__(BT)
void render_scan(const float4* __restrict__ pa, const float4* __restrict__ pb,
                 const float4* __restrict__ pc, float* __restrict__ out, int n) {
  __shared__ unsigned long long s_zkey[CAP];
  __shared__ unsigned long long s_dkey[CAP];
  __shared__ int s_rank[K];
  __shared__ float4 s_p0[K];
  __shared__ float4 s_p1[K];
  __shared__ float2 s_p2[K];
  __shared__ float4 s_part[BT];
  __shared__ int s_cnt;

  const int t  = (int)blockIdx.x;
  const int tx = t % NTX;
  const int ty = t / NTX;
  const int tid = (int)threadIdx.x;
  const int lane = tid & 63;
  const float cxc = (tx * TILE + TILE * 0.5f - W * 0.5f) / FX;
  const float cyc = (ty * TILE + TILE * 0.5f - H * 0.5f) / FY;

  if (tid == 0) s_cnt = 0;
  if (tid < K) s_rank[tid] = 0;
  __syncthreads();

  for (int g = tid; g < n; g += BT) {
    float4 v = pa[g];
    float ddx = cxc - v.x, ddy = cyc - v.y;
    float dist = sqrtf(ddx * ddx + ddy * ddy);
    bool hit = (v.z >= 0.0f) && (dist <= v.z);
    unsigned long long m = __ballot(hit);
    if (m) {
      int leader = __ffsll((long long)m) - 1;
      int base = 0;
      if (lane == leader) base = atomicAdd(&s_cnt, __popcll(m));
      base = __shfl(base, leader, 64);
      if (hit) {
        int slot = base + __popcll(m & ((1ull << lane) - 1ull));
        if (slot < CAP) {
          s_dkey[slot] = ((unsigned long long)__float_as_uint(dist) << 32) |
                         (unsigned int)g;
          s_zkey[slot] = ((unsigned long long)__float_as_uint(v.w) << 32) |
                         (unsigned int)g;
        }
      }
    }
  }
  __syncthreads();
  int cnt = min(s_cnt, CAP);
  int cnt2 = cnt;

  if (cnt > K) {
    int M = 512; while (M < cnt) M <<= 1;
    for (int i = cnt + tid; i < M; i += BT) s_dkey[i] = ~0ull;
    hsort1(s_dkey, M);
    if (tid < K) {
      int g = (int)(s_dkey[tid] & 0xffffffffu);
      s_zkey[tid] = ((unsigned long long)__float_as_uint(pa[g].w) << 32) |
                    (unsigned int)g;
    }
    __syncthreads();
    cnt2 = K;
  }

  // rank sort
  {
    const int e = tid & 255;
    const int q = tid >> 8;
    if (e < cnt2) {
      unsigned long long mykey = s_zkey[e];
      int jlo = q * 64;
      int jhi = min(cnt2, jlo + 64);
      int partial = 0;
      for (int j = jlo; j < jhi; ++j)
        partial += (s_zkey[j] < mykey) ? 1 : 0;
      if (partial) atomicAdd(&s_rank[e], partial);
    }
  }
  __syncthreads();
  if (tid < cnt2) {
    int g = (int)(s_zkey[tid] & 0xffffffffu);
    int r = s_rank[tid];
    float4 A = pa[g], B = pb[g], C = pc[g];
    s_p0[r] = make_float4(A.x, A.y, B.x, B.y);
    s_p1[r] = make_float4(B.z, B.w, C.x, C.y);
    s_p2[r] = make_float2(C.z, C.w);
  }
  __syncthreads();
  const int p    = tid & 255;
  const int q    = tid >> 8;
  const int prow = p / TILE, pcol = p % TILE;
  const float u = ((float)(tx * TILE + pcol) + 0.5f - W * 0.5f) / FX;
  const float v = ((float)(ty * TILE + prow) + 0.5f - H * 0.5f) / FY;
  const int chunk = (cnt2 + 3) >> 2;
  const int k0 = q * chunk;
  const int k1 = min(cnt2, k0 + chunk);
  float T = 1.0f, accr = 0.0f, accg = 0.0f, accb = 0.0f;
  for (int k2 = k0; k2 < k1; ++k2) {
    float4 p0 = s_p0[k2];
    float4 p1 = s_p1[k2];
    float2 p2 = s_p2[k2];
    float dx = u - p0.x;
    float dy = v - p0.y;
    float maha = (p1.x*dx*dx - 2.0f*p0.w*dx*dy + p0.z*dy*dy) * p1.y;
    float alpha = fminf(p1.z * __expf(-0.5f * maha), 0.99f);
    float w = alpha * T;
    accr += w * p1.w;
    accg += w * p2.x;
    accb += w * p2.y;
    T *= (1.0f - alpha);
  }
  s_part[tid] = make_float4(accr, accg, accb, T);
  __syncthreads();
  if (q == 0) {
    float4 P0 = s_part[p];
    float4 P1 = s_part[p + 256];
    float4 P2 = s_part[p + 512];
    float4 P3 = s_part[p + 768];
    float r = P0.x + P0.w * (P1.x + P1.w * (P2.x + P2.w * P3.x));
    float g = P0.y + P0.w * (P1.y + P1.w * (P2.y + P2.w * P3.y));
    float b = P0.z + P0.w * (P1.z + P1.w * (P2.z + P2.w * P3.z));
    const int row = ty * TILE + prow;
    const int col = tx * TILE + pcol;
    const int o = (row * W + col) * 3;
    out[o+0] = fminf(fmaxf(r, 0.0f), 1.0f);
    out[o+1] = fminf(fmaxf(g, 0.0f), 1.0f);
    out[o+2] = fminf(fmaxf(b, 0.0f), 1.0f);
  }
}

extern "C" void kernel_launch(void* const* d_in, const int* in_sizes, int n_in,
                              void* d_out, int out_size, void* d_ws, size_t ws_size,
                              hipStream_t stream) {
  const float* pos  = (const float*)d_in[0];
  const float* rgb  = (const float*)d_in[1];
  const float* opac = (const float*)d_in[2];
  const float* quat = (const float*)d_in[3];
  const float* scl  = (const float*)d_in[4];
  const float* w2cr = (const float*)d_in[5];
  const float* w2ct = (const float*)d_in[6];
  float* out = (float*)d_out;
  const int n = in_sizes[0] / 3;
  const int nb = (n + 255) / 256;

  char* ws = (char*)d_ws;
  float4* pa = (float4*)(ws + A_OFF);
  float4* pb = (float4*)(ws + B_OFF);
  float4* pc = (float4*)(ws + C_OFF);
  int* seglen = (int*)(ws + SL_OFF);
  unsigned long long* listd = (unsigned long long*)(ws + LD_OFF);
  unsigned long long* listz = (unsigned long long*)(ws + LZ_OFF);
  float4* qa = (float4*)(ws + QA_OFF);
  float4* qb = (float4*)(ws + QB_OFF);
  float2* qc = (float2*)(ws + QC_OFF);
  int* qcnt = (int*)(ws + QN_OFF);

  if (ws_size >= WS_FULL && nb <= NB_MAX) {
    pre_bin_r<<<nb, 256, 0, stream>>>(
        pos, rgb, opac, quat, scl, w2cr, w2ct, pa, pb, pc, seglen, listd, listz, n);
    sort_k<<<NT, BT, 0, stream>>>(pa, pb, pc, seglen, listd, listz,
                                  qa, qb, qc, qcnt, nb);
    blend_k<<<NT, BT, 0, stream>>>(qa, qb, qc, qcnt, out);
  } else {
    pre_only<<<nb, 256, 0, stream>>>(pos, rgb, opac, quat, scl, w2cr, w2ct,
                                     pa, pb, pc, n);
    render_scan<<<NT, BT, 0, stream>>>(pa, pb, pc, out, n);
  }
}

// Round 10
// 22.261 us; speedup vs baseline: 11.7216x; 11.7216x over previous
//
#include <hip/hip_runtime.h>
#include <math.h>

namespace {
constexpr int W = 256, H = 256, TILE = 16, NTX = 16, NT = 256, K = 256;
constexpr float FX = 200.0f, FY = 200.0f, NEARP = 0.3f, MAGIC = 1.2f;
constexpr float LP = 0.3f / (FX * FX);
constexpr float HALF_W = W * MAGIC / 2.0f / FX;   // 0.768
constexpr float HALF_H = H * MAGIC / 2.0f / FY;   // 0.768
constexpr float THDIAG = 0.05656854249492381f;    // 0.5*sqrt((TILE/FX)^2+(TILE/FY)^2)
constexpr int CAP = 1024;        // cnt ~ 157 +- 12.5; 1024 = +70 sigma
constexpr int N_PAD = 10240;
constexpr int BT = 1024;
constexpr int NB_MAX = 64;
constexpr int SEG = 256;
// ws layout
constexpr size_t A_OFF  = 0;                                   // pa: (mx,my,radius,z)
constexpr size_t B_OFF  = A_OFF + (size_t)N_PAD * 16;          // pb: (cp2,bp2,ap2,lopa)
constexpr size_t C_OFF  = B_OFF + (size_t)N_PAD * 16;          // pc: (cr,cg,cb,0)
constexpr size_t SL_OFF = C_OFF + (size_t)N_PAD * 16;          // seglen[NT*NB_MAX]
constexpr size_t LD_OFF = SL_OFF + (size_t)NT * NB_MAX * 4;    // listd
constexpr size_t LZ_OFF = LD_OFF + (size_t)NT * NB_MAX * SEG * 8;  // listz
constexpr size_t WS_FULL = LZ_OFF + (size_t)NT * NB_MAX * SEG * 8;
}

struct Pre { float mx, my, z, a, b, c, radius; };

__device__ inline Pre preprocess(int g, const float* __restrict__ pos,
                                 const float* __restrict__ quat,
                                 const float* __restrict__ scl,
                                 const float* __restrict__ w2cr,
                                 const float* __restrict__ w2ct) {
  float p0 = pos[3*g+0], p1 = pos[3*g+1], p2 = pos[3*g+2];
  float qw = quat[4*g+0], qx = quat[4*g+1], qy = quat[4*g+2], qz = quat[4*g+3];
  float inv = 1.0f / sqrtf(qw*qw + qx*qx + qy*qy + qz*qz);
  qw *= inv; qx *= inv; qy *= inv; qz *= inv;
  float r00 = 1.f-2.f*(qy*qy+qz*qz), r01 = 2.f*(qx*qy-qw*qz), r02 = 2.f*(qx*qz+qw*qy);
  float r10 = 2.f*(qx*qy+qw*qz), r11 = 1.f-2.f*(qx*qx+qz*qz), r12 = 2.f*(qy*qz-qw*qx);
  float r20 = 2.f*(qx*qz-qw*qy), r21 = 2.f*(qy*qz+qw*qx), r22 = 1.f-2.f*(qx*qx+qy*qy);
  float e0 = expf(scl[3*g+0]); float s0 = e0*e0;
  float e1 = expf(scl[3*g+1]); float s1 = e1*e1;
  float e2 = expf(scl[3*g+2]); float s2 = e2*e2;
  float C00 = r00*r00*s0 + r01*r01*s1 + r02*r02*s2;
  float C01 = r00*r10*s0 + r01*r11*s1 + r02*r12*s2;
  float C02 = r00*r20*s0 + r01*r21*s1 + r02*r22*s2;
  float C11 = r10*r10*s0 + r11*r11*s1 + r12*r12*s2;
  float C12 = r10*r20*s0 + r11*r21*s1 + r12*r22*s2;
  float C22 = r20*r20*s0 + r21*r21*s1 + r22*r22*s2;
  float w00=w2cr[0],w01=w2cr[1],w02=w2cr[2];
  float w10=w2cr[3],w11=w2cr[4],w12=w2cr[5];
  float w20=w2cr[6],w21=w2cr[7],w22=w2cr[8];
  float x = w00*p0 + w01*p1 + w02*p2 + w2ct[0];
  float y = w10*p0 + w11*p1 + w12*p2 + w2ct[1];
  float z = w20*p0 + w21*p1 + w22*p2 + w2ct[2];
  float m00 = w00*C00 + w01*C01 + w02*C02;
  float m01 = w00*C01 + w01*C11 + w02*C12;
  float m02 = w00*C02 + w01*C12 + w02*C22;
  float m10 = w10*C00 + w11*C01 + w12*C02;
  float m11 = w10*C01 + w11*C11 + w12*C12;
  float m12 = w10*C02 + w11*C12 + w12*C22;
  float m20 = w20*C00 + w21*C01 + w22*C02;
  float m21 = w20*C01 + w21*C11 + w22*C12;
  float m22 = w20*C02 + w21*C12 + w22*C22;
  float v00 = m00*w00 + m01*w01 + m02*w02;
  float v01 = m00*w10 + m01*w11 + m02*w12;
  float v02 = m00*w20 + m01*w21 + m02*w22;
  float v10 = m10*w00 + m11*w01 + m12*w02;
  float v11 = m10*w10 + m11*w11 + m12*w12;
  float v12 = m10*w20 + m11*w21 + m12*w22;
  float v20 = m20*w00 + m21*w01 + m22*w02;
  float v21 = m20*w10 + m21*w11 + m22*w12;
  float v22 = m20*w20 + m21*w21 + m22*w22;
  float zc = fmaxf(z, 1e-6f);
  float iz = 1.0f / zc;
  float mx = x * iz, my = y * iz;
  float iz2 = iz * iz;
  float jx = -x * iz2, jy = -y * iz2;
  float a00 = iz*v00 + jx*v20, a01 = iz*v01 + jx*v21, a02 = iz*v02 + jx*v22;
  float a10 = iz*v10 + jy*v20, a11 = iz*v11 + jy*v21, a12 = iz*v12 + jy*v22;
  float A  = a00*iz + a02*jx + LP;
  float Bv = a01*iz + a02*jy;
  float Cv = a11*iz + a12*jy + LP;
  float mid = 0.5f*(A + Cv);
  float hh  = 0.5f*(A - Cv);
  float disc = fmaxf(hh*hh + Bv*Bv, 0.0f);
  float smax = sqrtf(fmaxf(mid + sqrtf(disc), 1e-12f));
  bool infr = (z > NEARP) && (fabsf(mx) < HALF_W) && (fabsf(my) < HALF_H);
  Pre r;
  r.mx = mx; r.my = my; r.z = z; r.a = A; r.b = Bv; r.c = Cv;
  r.radius = infr ? (3.0f * smax + THDIAG) : -1.0f;
  return r;
}

// ---- preprocess + segmented binning; params stored blend-ready (prefolded) ----

template <bool BIN>
__global__ __launch_bounds__(256)
void pre_bin(const float* __restrict__ pos, const float* __restrict__ rgb,
             const float* __restrict__ opac, const float* __restrict__ quat,
             const float* __restrict__ scl, const float* __restrict__ w2cr,
             const float* __restrict__ w2ct,
             float4* __restrict__ pa, float4* __restrict__ pb,
             float4* __restrict__ pc, int* __restrict__ seglen,
             unsigned long long* __restrict__ listd,
             unsigned long long* __restrict__ listz, int n) {
  __shared__ int s_tc[NT];
  const int tid = (int)threadIdx.x;
  const int blk = (int)blockIdx.x;
  if (BIN) {
    if (tid < NT) s_tc[tid] = 0;
    __syncthreads();
  }
  const int g = blk * 256 + tid;
  if (g < n) {
    Pre p = preprocess(g, pos, quat, scl, w2cr, w2ct);
    float det = fmaxf(p.a * p.c - p.b * p.b, 1e-12f);
    float ivd = 1.0f / det;
    float lopa = -__logf(1.0f + __expf(-opac[g]));   // ln(sigmoid(o))
    pa[g] = make_float4(p.mx, p.my, p.radius, p.z);
    // exponent = cp2*dx^2 + bp2*dx*dy + ap2*dy^2 + lopa ; alpha = min(exp(.),.99)
    pb[g] = make_float4(-0.5f * ivd * p.c, ivd * p.b, -0.5f * ivd * p.a, lopa);
    pc[g] = make_float4(1.0f / (1.0f + __expf(-rgb[3*g+0])),
                        1.0f / (1.0f + __expf(-rgb[3*g+1])),
                        1.0f / (1.0f + __expf(-rgb[3*g+2])), 0.0f);
    if (BIN && p.radius >= 0.0f) {
      float r = p.radius;
      int txlo = max(0,     (int)floorf(((p.mx - r) * FX + 120.0f) * 0.0625f));
      int txhi = min(NTX-1, (int)ceilf (((p.mx + r) * FX + 120.0f) * 0.0625f));
      int tylo = max(0,     (int)floorf(((p.my - r) * FY + 120.0f) * 0.0625f));
      int tyhi = min(NTX-1, (int)ceilf (((p.my + r) * FY + 120.0f) * 0.0625f));
      unsigned long long gbits = (unsigned int)g;
      for (int ty = tylo; ty <= tyhi; ++ty) {
        float cy = (ty * TILE + TILE * 0.5f - H * 0.5f) / FY;
        float ddy = cy - p.my;
        for (int tx = txlo; tx <= txhi; ++tx) {
          float cx = (tx * TILE + TILE * 0.5f - W * 0.5f) / FX;
          float ddx = cx - p.mx;
          float dist = sqrtf(ddx * ddx + ddy * ddy);   // exact reference predicate
          if (dist <= r) {
            int t = ty * NTX + tx;
            int slot = atomicAdd(&s_tc[t], 1);   // < 256 per block => slot < SEG
            size_t idx = ((size_t)t * NB_MAX + blk) * SEG + slot;
            listd[idx] = ((unsigned long long)__float_as_uint(dist) << 32) | gbits;
            listz[idx] = ((unsigned long long)__float_as_uint(p.z)  << 32) | gbits;
          }
        }
      }
    }
  }
  if (BIN) {
    __syncthreads();
    if (tid < NT) seglen[(size_t)tid * NB_MAX + blk] = s_tc[tid];
  }
}

// ---- hybrid bitonic (rare cnt>K path only), M <= 1024, BT threads ----

__device__ inline void hsort1(unsigned long long* key, int M) {
  const int tid = (int)threadIdx.x;
  __syncthreads();
  unsigned long long e = (tid < M) ? key[tid] : ~0ull;
  for (int k = 2; k <= M; k <<= 1) {
    for (int j = k >> 1; j >= 64; j >>= 1) {
      __syncthreads();
      if (tid < M) key[tid] = e;
      __syncthreads();
      if (tid < M) {
        unsigned long long p = key[tid ^ j];
        bool takeMin = (((tid & j) == 0) == ((tid & k) == 0));
        e = ((p < e) == takeMin) ? p : e;   // keys unique
      }
    }
    int j0 = ((k >> 1) < 32) ? (k >> 1) : 32;
    for (int j = j0; j >= 1; j >>= 1) {
      unsigned long long p = __shfl_xor(e, j, 64);
      bool takeMin = (((tid & j) == 0) == ((tid & k) == 0));
      e = ((p < e) == takeMin) ? p : e;
    }
  }
  __syncthreads();
  if (tid < M) key[tid] = e;
  __syncthreads();
}

// ---- shared tail: rank z-sort -> scatter -> 2px/thread 8-split blend ----

__device__ inline void tail8(
    const float4* __restrict__ pa, const float4* __restrict__ pb,
    const float4* __restrict__ pc, float* __restrict__ out,
    unsigned long long* s_zkey, int* s_rank,
    float4* s_p0, float4* s_p1, float* s_cb, float4* s_part,
    int cnt2, int tx, int ty) {
  const int tid = (int)threadIdx.x;
  // rank sort by (z, idx): 4 quarter-counts per element, unique keys
  {
    const int e = tid & 255;
    const int q = tid >> 8;
    if (e < cnt2) {
      unsigned long long mykey = s_zkey[e];
      int jlo = q * 64;
      int jhi = min(cnt2, jlo + 64);
      int partial = 0;
      for (int j = jlo; j < jhi; ++j)
        partial += (s_zkey[j] < mykey) ? 1 : 0;
      if (partial) atomicAdd(&s_rank[e], partial);
    }
  }
  __syncthreads();
  // scatter blend-ready params to rank position
  if (tid < cnt2) {
    int g = (int)(s_zkey[tid] & 0xffffffffu);
    int r = s_rank[tid];
    float4 A = pa[g], B = pb[g], C = pc[g];
    s_p0[r] = make_float4(A.x, A.y, B.x, B.y);   // mx, my, cp2, bp2
    s_p1[r] = make_float4(B.z, B.w, C.x, C.y);   // ap2, lopa, cr, cg
    s_cb[r] = C.z;                               // cb
  }
  __syncthreads();

  // blend: thread (p7 = tid&127, q8 = tid>>7) does pixels p7 (rows 0-7)
  // and p7+128 (rows 8-15) for its 1/8 chunk of the sorted list.
  const int p7 = tid & 127;
  const int q8 = tid >> 7;
  const int prl = p7 >> 4;           // row (low half)
  const int pcol = p7 & 15;
  const float u   = ((float)(tx * TILE + pcol) + 0.5f - W * 0.5f) / FX;
  const float vlo = ((float)(ty * TILE + prl) + 0.5f - H * 0.5f) / FY;
  const float vhi = ((float)(ty * TILE + prl + 8) + 0.5f - H * 0.5f) / FY;
  const int chunk = (cnt2 + 7) >> 3;
  const int k0 = q8 * chunk;
  const int k1 = min(cnt2, k0 + chunk);
  float Tl = 1.0f, lr = 0.0f, lg = 0.0f, lb = 0.0f;
  float Th = 1.0f, hr = 0.0f, hg = 0.0f, hb = 0.0f;
  for (int k2 = k0; k2 < k1; ++k2) {
    float4 P0 = s_p0[k2];            // mx, my, cp2, bp2
    float4 P1 = s_p1[k2];            // ap2, lopa, cr, cg
    float cb = s_cb[k2];
    float dx = u - P0.x;
    float s  = fmaf(P0.z * dx, dx, P1.y);   // cp2*dx^2 + lopa
    float bd = P0.w * dx;                   // bp2*dx
    // low pixel
    float dyl = vlo - P0.y;
    float ml  = fmaf(fmaf(P1.x, dyl, bd), dyl, s);
    float al  = fminf(__expf(ml), 0.99f);
    float wl  = al * Tl;
    lr = fmaf(wl, P1.z, lr); lg = fmaf(wl, P1.w, lg); lb = fmaf(wl, cb, lb);
    Tl = fmaf(-al, Tl, Tl);
    // high pixel
    float dyh = vhi - P0.y;
    float mh  = fmaf(fmaf(P1.x, dyh, bd), dyh, s);
    float ah  = fminf(__expf(mh), 0.99f);
    float wh  = ah * Th;
    hr = fmaf(wh, P1.z, hr); hg = fmaf(wh, P1.w, hg); hb = fmaf(wh, cb, hb);
    Th = fmaf(-ah, Th, Th);
  }
  // partial for pixel px(0..255) of chunk q lives at s_part[q*256 + px]
  s_part[q8 * 256 + p7]       = make_float4(lr, lg, lb, Tl);
  s_part[q8 * 256 + 128 + p7] = make_float4(hr, hg, hb, Th);
  __syncthreads();

  if (tid < 256) {
    float4 P = s_part[7 * 256 + tid];
    float r = P.x, g = P.y, b = P.z;
    #pragma unroll
    for (int q = 6; q >= 0; --q) {
      float4 Q = s_part[q * 256 + tid];
      r = fmaf(Q.w, r, Q.x);
      g = fmaf(Q.w, g, Q.y);
      b = fmaf(Q.w, b, Q.z);
    }
    const int prow = tid / TILE, pcol2 = tid % TILE;
    const int row = ty * TILE + prow;
    const int col = tx * TILE + pcol2;
    const int o = (row * W + col) * 3;
    out[o+0] = fminf(fmaxf(r, 0.0f), 1.0f);
    out[o+1] = fminf(fmaxf(g, 0.0f), 1.0f);
    out[o+2] = fminf(fmaxf(b, 0.0f), 1.0f);
  }
}

// ---- render from prebuilt segmented lists: gather -> (topK) -> tail8 ----

__global__ __launch_bounds__(BT)
void render_list(const float4* __restrict__ pa, const float4* __restrict__ pb,
                 const float4* __restrict__ pc, const int* __restrict__ seglen,
                 const unsigned long long* __restrict__ listd,
                 const unsigned long long* __restrict__ listz,
                 float* __restrict__ out, int nb) {
  __shared__ unsigned long long s_zkey[CAP];
  __shared__ unsigned long long s_dkey[CAP];
  __shared__ int s_off[NB_MAX + 1];
  __shared__ int s_rank[K];
  __shared__ float4 s_p0[K];
  __shared__ float4 s_p1[K];
  __shared__ float  s_cb[K];
  __shared__ float4 s_part[8 * 256];

  const int t  = (int)blockIdx.x;
  const int tx = t % NTX;
  const int ty = t / NTX;
  const int tid = (int)threadIdx.x;

  if (tid < K) s_rank[tid] = 0;
  if (tid < 64) {
    int v = (tid < nb) ? seglen[(size_t)t * NB_MAX + tid] : 0;
    #pragma unroll
    for (int d = 1; d < 64; d <<= 1) {
      int u2 = __shfl_up(v, d, 64);
      if (tid >= d) v += u2;
    }
    if (tid == 0) s_off[0] = 0;
    if (tid < nb) s_off[tid + 1] = v;
  }
  __syncthreads();
  int cnt = min(s_off[nb], CAP);

  for (int i = tid; i < cnt; i += BT) {
    int lo = 0, hi = nb;
    while (hi - lo > 1) {
      int mid = (lo + hi) >> 1;
      if (s_off[mid] <= i) lo = mid; else hi = mid;
    }
    size_t src = ((size_t)t * NB_MAX + lo) * SEG + (size_t)(i - s_off[lo]);
    s_zkey[i] = listz[src];
  }
  __syncthreads();
  int cnt2 = cnt;

  if (cnt > K) {
    // rare: exact top-K by (dist, idx) ascending == top_k on -dist
    for (int i = tid; i < cnt; i += BT) {
      int lo = 0, hi = nb;
      while (hi - lo > 1) {
        int mid = (lo + hi) >> 1;
        if (s_off[mid] <= i) lo = mid; else hi = mid;
      }
      size_t src = ((size_t)t * NB_MAX + lo) * SEG + (size_t)(i - s_off[lo]);
      s_dkey[i] = listd[src];
    }
    int M = 512; while (M < cnt) M <<= 1;
    for (int i = cnt + tid; i < M; i += BT) s_dkey[i] = ~0ull;
    hsort1(s_dkey, M);
    if (tid < K) {
      int g = (int)(s_dkey[tid] & 0xffffffffu);
      s_zkey[tid] = ((unsigned long long)__float_as_uint(pa[g].w) << 32) |
                    (unsigned int)g;
    }
    __syncthreads();
    cnt2 = K;
  }

  tail8(pa, pb, pc, out, s_zkey, s_rank, s_p0, s_p1, s_cb, s_part, cnt2, tx, ty);
}

// ---- fallback: 2-kernel scan path (ws too small) ----

__global__ __launch_bounds__(BT)
void render_scan(const float4* __restrict__ pa, const float4* __restrict__ pb,
                 const float4* __restrict__ pc, float* __restrict__ out, int n) {
  __shared__ unsigned long long s_zkey[CAP];
  __shared__ unsigned long long s_dkey[CAP];
  __shared__ int s_rank[K];
  __shared__ float4 s_p0[K];
  __shared__ float4 s_p1[K];
  __shared__ float  s_cb[K];
  __shared__ float4 s_part[8 * 256];
  __shared__ int s_cnt;

  const int t  = (int)blockIdx.x;
  const int tx = t % NTX;
  const int ty = t / NTX;
  const int tid = (int)threadIdx.x;
  const int lane = tid & 63;
  const float cxc = (tx * TILE + TILE * 0.5f - W * 0.5f) / FX;
  const float cyc = (ty * TILE + TILE * 0.5f - H * 0.5f) / FY;

  if (tid == 0) s_cnt = 0;
  if (tid < K) s_rank[tid] = 0;
  __syncthreads();

  for (int g = tid; g < n; g += BT) {
    float4 v = pa[g];
    float ddx = cxc - v.x, ddy = cyc - v.y;
    float dist = sqrtf(ddx * ddx + ddy * ddy);
    bool hit = (v.z >= 0.0f) && (dist <= v.z);
    unsigned long long m = __ballot(hit);
    if (m) {
      int leader = __ffsll((long long)m) - 1;
      int base = 0;
      if (lane == leader) base = atomicAdd(&s_cnt, __popcll(m));
      base = __shfl(base, leader, 64);
      if (hit) {
        int slot = base + __popcll(m & ((1ull << lane) - 1ull));
        if (slot < CAP) {
          s_dkey[slot] = ((unsigned long long)__float_as_uint(dist) << 32) |
                         (unsigned int)g;
          s_zkey[slot] = ((unsigned long long)__float_as_uint(v.w) << 32) |
                         (unsigned int)g;
        }
      }
    }
  }
  __syncthreads();
  int cnt = min(s_cnt, CAP);
  int cnt2 = cnt;

  if (cnt > K) {
    int M = 512; while (M < cnt) M <<= 1;
    for (int i = cnt + tid; i < M; i += BT) s_dkey[i] = ~0ull;
    hsort1(s_dkey, M);
    if (tid < K) {
      int g = (int)(s_dkey[tid] & 0xffffffffu);
      s_zkey[tid] = ((unsigned long long)__float_as_uint(pa[g].w) << 32) |
                    (unsigned int)g;
    }
    __syncthreads();
    cnt2 = K;
  }

  tail8(pa, pb, pc, out, s_zkey, s_rank, s_p0, s_p1, s_cb, s_part, cnt2, tx, ty);
}

extern "C" void kernel_launch(void* const* d_in, const int* in_sizes, int n_in,
                              void* d_out, int out_size, void* d_ws, size_t ws_size,
                              hipStream_t stream) {
  const float* pos  = (const float*)d_in[0];
  const float* rgb  = (const float*)d_in[1];
  const float* opac = (const float*)d_in[2];
  const float* quat = (const float*)d_in[3];
  const float* scl  = (const float*)d_in[4];
  const float* w2cr = (const float*)d_in[5];
  const float* w2ct = (const float*)d_in[6];
  float* out = (float*)d_out;
  const int n = in_sizes[0] / 3;
  const int nb = (n + 255) / 256;

  char* ws = (char*)d_ws;
  float4* pa = (float4*)(ws + A_OFF);
  float4* pb = (float4*)(ws + B_OFF);
  float4* pc = (float4*)(ws + C_OFF);
  int* seglen = (int*)(ws + SL_OFF);
  unsigned long long* listd = (unsigned long long*)(ws + LD_OFF);
  unsigned long long* listz = (unsigned long long*)(ws + LZ_OFF);

  if (ws_size >= WS_FULL && nb <= NB_MAX) {
    pre_bin<true><<<nb, 256, 0, stream>>>(
        pos, rgb, opac, quat, scl, w2cr, w2ct, pa, pb, pc, seglen, listd, listz, n);
    render_list<<<NT, BT, 0, stream>>>(pa, pb, pc, seglen, listd, listz, out, nb);
  } else {
    pre_bin<false><<<nb, 256, 0, stream>>>(
        pos, rgb, opac, quat, scl, w2cr, w2ct, pa, pb, pc, seglen, listd, listz, n);
    render_scan<<<NT, BT, 0, stream>>>(pa, pb, pc, out, n);
  }
}

// Round 11
// 21.071 us; speedup vs baseline: 12.3835x; 1.0565x over previous
//
#include <hip/hip_runtime.h>
#include <math.h>

namespace {
constexpr int W = 256, H = 256, TILE = 16, NTX = 16, NT = 256, K = 256;
constexpr float FX = 200.0f, FY = 200.0f, NEARP = 0.3f, MAGIC = 1.2f;
constexpr float LP = 0.3f / (FX * FX);
constexpr float HALF_W = W * MAGIC / 2.0f / FX;   // 0.768
constexpr float HALF_H = H * MAGIC / 2.0f / FY;   // 0.768
constexpr float THDIAG = 0.05656854249492381f;    // 0.5*sqrt((TILE/FX)^2+(TILE/FY)^2)
constexpr int CAP = 1024;        // cnt ~ 157 +- 12.5; 1024 = +70 sigma
constexpr int N_PAD = 10240;
constexpr int BT = 1024;
constexpr int NB_MAX = 64;
constexpr int SEG = 256;
constexpr int NSPL = 16;         // blend split factor (4 px/thread)
// ws layout
constexpr size_t A_OFF  = 0;                                   // pa: (mx,my,radius,z)
constexpr size_t B_OFF  = A_OFF + (size_t)N_PAD * 16;          // pb: (cp2,bp2,ap2,lopa)
constexpr size_t C_OFF  = B_OFF + (size_t)N_PAD * 16;          // pc: (cr,cg,cb,0)
constexpr size_t SL_OFF = C_OFF + (size_t)N_PAD * 16;          // seglen[NT*NB_MAX]
constexpr size_t LD_OFF = SL_OFF + (size_t)NT * NB_MAX * 4;    // listd
constexpr size_t LZ_OFF = LD_OFF + (size_t)NT * NB_MAX * SEG * 8;  // listz
constexpr size_t WS_FULL = LZ_OFF + (size_t)NT * NB_MAX * SEG * 8;
}

struct Pre { float mx, my, z, a, b, c, radius; };

__device__ inline Pre preprocess(int g, const float* __restrict__ pos,
                                 const float* __restrict__ quat,
                                 const float* __restrict__ scl,
                                 const float* __restrict__ w2cr,
                                 const float* __restrict__ w2ct) {
  float p0 = pos[3*g+0], p1 = pos[3*g+1], p2 = pos[3*g+2];
  float qw = quat[4*g+0], qx = quat[4*g+1], qy = quat[4*g+2], qz = quat[4*g+3];
  float inv = 1.0f / sqrtf(qw*qw + qx*qx + qy*qy + qz*qz);
  qw *= inv; qx *= inv; qy *= inv; qz *= inv;
  float r00 = 1.f-2.f*(qy*qy+qz*qz), r01 = 2.f*(qx*qy-qw*qz), r02 = 2.f*(qx*qz+qw*qy);
  float r10 = 2.f*(qx*qy+qw*qz), r11 = 1.f-2.f*(qx*qx+qz*qz), r12 = 2.f*(qy*qz-qw*qx);
  float r20 = 2.f*(qx*qz-qw*qy), r21 = 2.f*(qy*qz+qw*qx), r22 = 1.f-2.f*(qx*qx+qy*qy);
  float e0 = __expf(scl[3*g+0]); float s0 = e0*e0;
  float e1 = __expf(scl[3*g+1]); float s1 = e1*e1;
  float e2 = __expf(scl[3*g+2]); float s2 = e2*e2;
  float C00 = r00*r00*s0 + r01*r01*s1 + r02*r02*s2;
  float C01 = r00*r10*s0 + r01*r11*s1 + r02*r12*s2;
  float C02 = r00*r20*s0 + r01*r21*s1 + r02*r22*s2;
  float C11 = r10*r10*s0 + r11*r11*s1 + r12*r12*s2;
  float C12 = r10*r20*s0 + r11*r21*s1 + r12*r22*s2;
  float C22 = r20*r20*s0 + r21*r21*s1 + r22*r22*s2;
  float w00=w2cr[0],w01=w2cr[1],w02=w2cr[2];
  float w10=w2cr[3],w11=w2cr[4],w12=w2cr[5];
  float w20=w2cr[6],w21=w2cr[7],w22=w2cr[8];
  float x = w00*p0 + w01*p1 + w02*p2 + w2ct[0];
  float y = w10*p0 + w11*p1 + w12*p2 + w2ct[1];
  float z = w20*p0 + w21*p1 + w22*p2 + w2ct[2];
  float m00 = w00*C00 + w01*C01 + w02*C02;
  float m01 = w00*C01 + w01*C11 + w02*C12;
  float m02 = w00*C02 + w01*C12 + w02*C22;
  float m10 = w10*C00 + w11*C01 + w12*C02;
  float m11 = w10*C01 + w11*C11 + w12*C12;
  float m12 = w10*C02 + w11*C12 + w12*C22;
  float m20 = w20*C00 + w21*C01 + w22*C02;
  float m21 = w20*C01 + w21*C11 + w22*C12;
  float m22 = w20*C02 + w21*C12 + w22*C22;
  float v00 = m00*w00 + m01*w01 + m02*w02;
  float v01 = m00*w10 + m01*w11 + m02*w12;
  float v02 = m00*w20 + m01*w21 + m02*w22;
  float v10 = m10*w00 + m11*w01 + m12*w02;
  float v11 = m10*w10 + m11*w11 + m12*w12;
  float v12 = m10*w20 + m11*w21 + m12*w22;
  float v20 = m20*w00 + m21*w01 + m22*w02;
  float v21 = m20*w10 + m21*w11 + m22*w12;
  float v22 = m20*w20 + m21*w21 + m22*w22;
  float zc = fmaxf(z, 1e-6f);
  float iz = 1.0f / zc;
  float mx = x * iz, my = y * iz;
  float iz2 = iz * iz;
  float jx = -x * iz2, jy = -y * iz2;
  float a00 = iz*v00 + jx*v20, a01 = iz*v01 + jx*v21, a02 = iz*v02 + jx*v22;
  float a10 = iz*v10 + jy*v20, a11 = iz*v11 + jy*v21, a12 = iz*v12 + jy*v22;
  float A  = a00*iz + a02*jx + LP;
  float Bv = a01*iz + a02*jy;
  float Cv = a11*iz + a12*jy + LP;
  float mid = 0.5f*(A + Cv);
  float hh  = 0.5f*(A - Cv);
  float disc = fmaxf(hh*hh + Bv*Bv, 0.0f);
  float smax = sqrtf(fmaxf(mid + sqrtf(disc), 1e-12f));
  bool infr = (z > NEARP) && (fabsf(mx) < HALF_W) && (fabsf(my) < HALF_H);
  Pre r;
  r.mx = mx; r.my = my; r.z = z; r.a = A; r.b = Bv; r.c = Cv;
  r.radius = infr ? (3.0f * smax + THDIAG) : -1.0f;
  return r;
}

// ---- preprocess + segmented binning; params stored blend-ready (prefolded) ----

template <bool BIN>
__global__ __launch_bounds__(256)
void pre_bin(const float* __restrict__ pos, const float* __restrict__ rgb,
             const float* __restrict__ opac, const float* __restrict__ quat,
             const float* __restrict__ scl, const float* __restrict__ w2cr,
             const float* __restrict__ w2ct,
             float4* __restrict__ pa, float4* __restrict__ pb,
             float4* __restrict__ pc, int* __restrict__ seglen,
             unsigned long long* __restrict__ listd,
             unsigned long long* __restrict__ listz, int n) {
  __shared__ int s_tc[NT];
  const int tid = (int)threadIdx.x;
  const int blk = (int)blockIdx.x;
  if (BIN) {
    if (tid < NT) s_tc[tid] = 0;
    __syncthreads();
  }
  const int g = blk * 256 + tid;
  if (g < n) {
    Pre p = preprocess(g, pos, quat, scl, w2cr, w2ct);
    float det = fmaxf(p.a * p.c - p.b * p.b, 1e-12f);
    float ivd = 1.0f / det;
    float lopa = -__logf(1.0f + __expf(-opac[g]));   // ln(sigmoid(o))
    pa[g] = make_float4(p.mx, p.my, p.radius, p.z);
    // exponent = cp2*dx^2 + bp2*dx*dy + ap2*dy^2 + lopa ; alpha = min(exp(.),.99)
    pb[g] = make_float4(-0.5f * ivd * p.c, ivd * p.b, -0.5f * ivd * p.a, lopa);
    pc[g] = make_float4(1.0f / (1.0f + __expf(-rgb[3*g+0])),
                        1.0f / (1.0f + __expf(-rgb[3*g+1])),
                        1.0f / (1.0f + __expf(-rgb[3*g+2])), 0.0f);
    if (BIN && p.radius >= 0.0f) {
      float r = p.radius;
      int txlo = max(0,     (int)floorf(((p.mx - r) * FX + 120.0f) * 0.0625f));
      int txhi = min(NTX-1, (int)ceilf (((p.mx + r) * FX + 120.0f) * 0.0625f));
      int tylo = max(0,     (int)floorf(((p.my - r) * FY + 120.0f) * 0.0625f));
      int tyhi = min(NTX-1, (int)ceilf (((p.my + r) * FY + 120.0f) * 0.0625f));
      unsigned long long gbits = (unsigned int)g;
      for (int ty = tylo; ty <= tyhi; ++ty) {
        float cy = (ty * TILE + TILE * 0.5f - H * 0.5f) / FY;
        float ddy = cy - p.my;
        for (int tx = txlo; tx <= txhi; ++tx) {
          float cx = (tx * TILE + TILE * 0.5f - W * 0.5f) / FX;
          float ddx = cx - p.mx;
          float dist = sqrtf(ddx * ddx + ddy * ddy);   // exact reference predicate
          if (dist <= r) {
            int t = ty * NTX + tx;
            int slot = atomicAdd(&s_tc[t], 1);   // < 256 per block => slot < SEG
            size_t idx = ((size_t)t * NB_MAX + blk) * SEG + slot;
            listd[idx] = ((unsigned long long)__float_as_uint(dist) << 32) | gbits;
            listz[idx] = ((unsigned long long)__float_as_uint(p.z)  << 32) | gbits;
          }
        }
      }
    }
  }
  if (BIN) {
    __syncthreads();
    if (tid < NT) seglen[(size_t)tid * NB_MAX + blk] = s_tc[tid];
  }
}

// ---- hybrid bitonic (rare cnt>K path only), M <= 1024, BT threads ----

__device__ inline void hsort1(unsigned long long* key, int M) {
  const int tid = (int)threadIdx.x;
  __syncthreads();
  unsigned long long e = (tid < M) ? key[tid] : ~0ull;
  for (int k = 2; k <= M; k <<= 1) {
    for (int j = k >> 1; j >= 64; j >>= 1) {
      __syncthreads();
      if (tid < M) key[tid] = e;
      __syncthreads();
      if (tid < M) {
        unsigned long long p = key[tid ^ j];
        bool takeMin = (((tid & j) == 0) == ((tid & k) == 0));
        e = ((p < e) == takeMin) ? p : e;   // keys unique
      }
    }
    int j0 = ((k >> 1) < 32) ? (k >> 1) : 32;
    for (int j = j0; j >= 1; j >>= 1) {
      unsigned long long p = __shfl_xor(e, j, 64);
      bool takeMin = (((tid & j) == 0) == ((tid & k) == 0));
      e = ((p < e) == takeMin) ? p : e;
    }
  }
  __syncthreads();
  if (tid < M) key[tid] = e;
  __syncthreads();
}

// ---- shared tail: rank z-sort -> scatter -> 4px/thread 16-split blend ----

__device__ inline void tail16(
    const float4* __restrict__ pa, const float4* __restrict__ pb,
    const float4* __restrict__ pc, float* __restrict__ out,
    unsigned long long* s_zkey, int* s_rank,
    float4* s_p0, float4* s_p1, float* s_cb, float4* s_part,
    int cnt2, int tx, int ty) {
  const int tid = (int)threadIdx.x;
  // rank sort by (z, idx): 4 balanced quarter-counts per element, unique keys
  {
    const int e = tid & 255;
    const int q = tid >> 8;
    const int rchunk = (cnt2 + 3) >> 2;
    if (e < cnt2) {
      unsigned long long mykey = s_zkey[e];
      int jlo = q * rchunk;
      int jhi = min(cnt2, jlo + rchunk);
      int partial = 0;
      for (int j = jlo; j < jhi; ++j)
        partial += (s_zkey[j] < mykey) ? 1 : 0;
      if (partial) atomicAdd(&s_rank[e], partial);
    }
  }
  __syncthreads();
  // scatter blend-ready params to rank position
  if (tid < cnt2) {
    int g = (int)(s_zkey[tid] & 0xffffffffu);
    int r = s_rank[tid];
    float4 A = pa[g], B = pb[g], C = pc[g];
    s_p0[r] = make_float4(A.x, A.y, B.x, B.y);   // mx, my, cp2, bp2
    s_p1[r] = make_float4(B.z, B.w, C.x, C.y);   // ap2, lopa, cr, cg
    s_cb[r] = C.z;                               // cb
  }
  __syncthreads();

  // blend: thread (p6 = tid&63, q16 = tid>>6) does pixels (prow0+4s, pcol)
  // s=0..3 for its 1/16 chunk of the sorted list. Same column -> dx shared.
  const int p6  = tid & 63;
  const int q16 = tid >> 6;
  const int prow0 = p6 >> 4;         // 0..3
  const int pcol  = p6 & 15;
  const float u  = ((float)(tx * TILE + pcol) + 0.5f - W * 0.5f) / FX;
  const float v0 = ((float)(ty * TILE + prow0 +  0) + 0.5f - H * 0.5f) / FY;
  const float v1 = ((float)(ty * TILE + prow0 +  4) + 0.5f - H * 0.5f) / FY;
  const float v2 = ((float)(ty * TILE + prow0 +  8) + 0.5f - H * 0.5f) / FY;
  const float v3 = ((float)(ty * TILE + prow0 + 12) + 0.5f - H * 0.5f) / FY;
  const int chunk = (cnt2 + NSPL - 1) / NSPL;
  const int k0 = q16 * chunk;
  const int k1 = min(cnt2, k0 + chunk);
  float T0 = 1.0f, r0 = 0.0f, g0 = 0.0f, b0 = 0.0f;
  float T1 = 1.0f, r1 = 0.0f, g1 = 0.0f, b1 = 0.0f;
  float T2 = 1.0f, r2 = 0.0f, g2 = 0.0f, b2 = 0.0f;
  float T3 = 1.0f, r3 = 0.0f, g3 = 0.0f, b3 = 0.0f;
  for (int k2 = k0; k2 < k1; ++k2) {
    float4 P0 = s_p0[k2];            // mx, my, cp2, bp2
    float4 P1 = s_p1[k2];            // ap2, lopa, cr, cg
    float cb = s_cb[k2];
    float dx = u - P0.x;
    float s  = fmaf(P0.z * dx, dx, P1.y);   // cp2*dx^2 + lopa
    float bd = P0.w * dx;                   // bp2*dx
    {
      float dy = v0 - P0.y;
      float m  = fmaf(fmaf(P1.x, dy, bd), dy, s);
      float a  = fminf(__expf(m), 0.99f);
      float w  = a * T0;
      r0 = fmaf(w, P1.z, r0); g0 = fmaf(w, P1.w, g0); b0 = fmaf(w, cb, b0);
      T0 = fmaf(-a, T0, T0);
    }
    {
      float dy = v1 - P0.y;
      float m  = fmaf(fmaf(P1.x, dy, bd), dy, s);
      float a  = fminf(__expf(m), 0.99f);
      float w  = a * T1;
      r1 = fmaf(w, P1.z, r1); g1 = fmaf(w, P1.w, g1); b1 = fmaf(w, cb, b1);
      T1 = fmaf(-a, T1, T1);
    }
    {
      float dy = v2 - P0.y;
      float m  = fmaf(fmaf(P1.x, dy, bd), dy, s);
      float a  = fminf(__expf(m), 0.99f);
      float w  = a * T2;
      r2 = fmaf(w, P1.z, r2); g2 = fmaf(w, P1.w, g2); b2 = fmaf(w, cb, b2);
      T2 = fmaf(-a, T2, T2);
    }
    {
      float dy = v3 - P0.y;
      float m  = fmaf(fmaf(P1.x, dy, bd), dy, s);
      float a  = fminf(__expf(m), 0.99f);
      float w  = a * T3;
      r3 = fmaf(w, P1.z, r3); g3 = fmaf(w, P1.w, g3); b3 = fmaf(w, cb, b3);
      T3 = fmaf(-a, T3, T3);
    }
  }
  // pixel id = p6 + 64*s ; partial for chunk q at s_part[q*256 + pixel]
  s_part[q16 * 256 + p6 +   0] = make_float4(r0, g0, b0, T0);
  s_part[q16 * 256 + p6 +  64] = make_float4(r1, g1, b1, T1);
  s_part[q16 * 256 + p6 + 128] = make_float4(r2, g2, b2, T2);
  s_part[q16 * 256 + p6 + 192] = make_float4(r3, g3, b3, T3);
  __syncthreads();

  if (tid < 256) {
    float4 P = s_part[(NSPL - 1) * 256 + tid];
    float r = P.x, g = P.y, b = P.z;
    #pragma unroll
    for (int q = NSPL - 2; q >= 0; --q) {
      float4 Q = s_part[q * 256 + tid];
      r = fmaf(Q.w, r, Q.x);
      g = fmaf(Q.w, g, Q.y);
      b = fmaf(Q.w, b, Q.z);
    }
    // pixel id tid = p6 + 64*s -> prow = (tid&48)>>4 ... recover row/col:
    const int p6o = tid & 63;
    const int sub = tid >> 6;
    const int prow = (p6o >> 4) + 4 * sub;
    const int pcol2 = p6o & 15;
    const int row = ty * TILE + prow;
    const int col = tx * TILE + pcol2;
    const int o = (row * W + col) * 3;
    out[o+0] = fminf(fmaxf(r, 0.0f), 1.0f);
    out[o+1] = fminf(fmaxf(g, 0.0f), 1.0f);
    out[o+2] = fminf(fmaxf(b, 0.0f), 1.0f);
  }
}

// ---- render from prebuilt segmented lists: gather -> (topK) -> tail16 ----

__global__ __launch_bounds__(BT)
void render_list(const float4* __restrict__ pa, const float4* __restrict__ pb,
                 const float4* __restrict__ pc, const int* __restrict__ seglen,
                 const unsigned long long* __restrict__ listd,
                 const unsigned long long* __restrict__ listz,
                 float* __restrict__ out, int nb) {
  __shared__ unsigned long long s_zkey[CAP];
  __shared__ unsigned long long s_dkey[CAP];
  __shared__ int s_off[NB_MAX + 1];
  __shared__ int s_rank[K];
  __shared__ float4 s_p0[K];
  __shared__ float4 s_p1[K];
  __shared__ float  s_cb[K];
  __shared__ float4 s_part[NSPL * 256];

  const int t  = (int)blockIdx.x;
  const int tx = t % NTX;
  const int ty = t / NTX;
  const int tid = (int)threadIdx.x;

  if (tid < K) s_rank[tid] = 0;
  if (tid < 64) {
    int v = (tid < nb) ? seglen[(size_t)t * NB_MAX + tid] : 0;
    #pragma unroll
    for (int d = 1; d < 64; d <<= 1) {
      int u2 = __shfl_up(v, d, 64);
      if (tid >= d) v += u2;
    }
    if (tid == 0) s_off[0] = 0;
    if (tid < nb) s_off[tid + 1] = v;
  }
  __syncthreads();
  int cnt = min(s_off[nb], CAP);

  for (int i = tid; i < cnt; i += BT) {
    int lo = 0, hi = nb;
    while (hi - lo > 1) {
      int mid = (lo + hi) >> 1;
      if (s_off[mid] <= i) lo = mid; else hi = mid;
    }
    size_t src = ((size_t)t * NB_MAX + lo) * SEG + (size_t)(i - s_off[lo]);
    s_zkey[i] = listz[src];
  }
  __syncthreads();
  int cnt2 = cnt;

  if (cnt > K) {
    // rare: exact top-K by (dist, idx) ascending == top_k on -dist
    for (int i = tid; i < cnt; i += BT) {
      int lo = 0, hi = nb;
      while (hi - lo > 1) {
        int mid = (lo + hi) >> 1;
        if (s_off[mid] <= i) lo = mid; else hi = mid;
      }
      size_t src = ((size_t)t * NB_MAX + lo) * SEG + (size_t)(i - s_off[lo]);
      s_dkey[i] = listd[src];
    }
    int M = 512; while (M < cnt) M <<= 1;
    for (int i = cnt + tid; i < M; i += BT) s_dkey[i] = ~0ull;
    hsort1(s_dkey, M);
    if (tid < K) {
      int g = (int)(s_dkey[tid] & 0xffffffffu);
      s_zkey[tid] = ((unsigned long long)__float_as_uint(pa[g].w) << 32) |
                    (unsigned int)g;
    }
    __syncthreads();
    cnt2 = K;
  }

  tail16(pa, pb, pc, out, s_zkey, s_rank, s_p0, s_p1, s_cb, s_part, cnt2, tx, ty);
}

// ---- fallback: 2-kernel scan path (ws too small) ----

__global__ __launch_bounds__(BT)
void render_scan(const float4* __restrict__ pa, const float4* __restrict__ pb,
                 const float4* __restrict__ pc, float* __restrict__ out, int n) {
  __shared__ unsigned long long s_zkey[CAP];
  __shared__ unsigned long long s_dkey[CAP];
  __shared__ int s_rank[K];
  __shared__ float4 s_p0[K];
  __shared__ float4 s_p1[K];
  __shared__ float  s_cb[K];
  __shared__ float4 s_part[NSPL * 256];
  __shared__ int s_cnt;

  const int t  = (int)blockIdx.x;
  const int tx = t % NTX;
  const int ty = t / NTX;
  const int tid = (int)threadIdx.x;
  const int lane = tid & 63;
  const float cxc = (tx * TILE + TILE * 0.5f - W * 0.5f) / FX;
  const float cyc = (ty * TILE + TILE * 0.5f - H * 0.5f) / FY;

  if (tid == 0) s_cnt = 0;
  if (tid < K) s_rank[tid] = 0;
  __syncthreads();

  for (int g = tid; g < n; g += BT) {
    float4 v = pa[g];
    float ddx = cxc - v.x, ddy = cyc - v.y;
    float dist = sqrtf(ddx * ddx + ddy * ddy);
    bool hit = (v.z >= 0.0f) && (dist <= v.z);
    unsigned long long m = __ballot(hit);
    if (m) {
      int leader = __ffsll((long long)m) - 1;
      int base = 0;
      if (lane == leader) base = atomicAdd(&s_cnt, __popcll(m));
      base = __shfl(base, leader, 64);
      if (hit) {
        int slot = base + __popcll(m & ((1ull << lane) - 1ull));
        if (slot < CAP) {
          s_dkey[slot] = ((unsigned long long)__float_as_uint(dist) << 32) |
                         (unsigned int)g;
          s_zkey[slot] = ((unsigned long long)__float_as_uint(v.w) << 32) |
                         (unsigned int)g;
        }
      }
    }
  }
  __syncthreads();
  int cnt = min(s_cnt, CAP);
  int cnt2 = cnt;

  if (cnt > K) {
    int M = 512; while (M < cnt) M <<= 1;
    for (int i = cnt + tid; i < M; i += BT) s_dkey[i] = ~0ull;
    hsort1(s_dkey, M);
    if (tid < K) {
      int g = (int)(s_dkey[tid] & 0xffffffffu);
      s_zkey[tid] = ((unsigned long long)__float_as_uint(pa[g].w) << 32) |
                    (unsigned int)g;
    }
    __syncthreads();
    cnt2 = K;
  }

  tail16(pa, pb, pc, out, s_zkey, s_rank, s_p0, s_p1, s_cb, s_part, cnt2, tx, ty);
}

extern "C" void kernel_launch(void* const* d_in, const int* in_sizes, int n_in,
                              void* d_out, int out_size, void* d_ws, size_t ws_size,
                              hipStream_t stream) {
  const float* pos  = (const float*)d_in[0];
  const float* rgb  = (const float*)d_in[1];
  const float* opac = (const float*)d_in[2];
  const float* quat = (const float*)d_in[3];
  const float* scl  = (const float*)d_in[4];
  const float* w2cr = (const float*)d_in[5];
  const float* w2ct = (const float*)d_in[6];
  float* out = (float*)d_out;
  const int n = in_sizes[0] / 3;
  const int nb = (n + 255) / 256;

  char* ws = (char*)d_ws;
  float4* pa = (float4*)(ws + A_OFF);
  float4* pb = (float4*)(ws + B_OFF);
  float4* pc = (float4*)(ws + C_OFF);
  int* seglen = (int*)(ws + SL_OFF);
  unsigned long long* listd = (unsigned long long*)(ws + LD_OFF);
  unsigned long long* listz = (unsigned long long*)(ws + LZ_OFF);

  if (ws_size >= WS_FULL && nb <= NB_MAX) {
    pre_bin<true><<<nb, 256, 0, stream>>>(
        pos, rgb, opac, quat, scl, w2cr, w2ct, pa, pb, pc, seglen, listd, listz, n);
    render_list<<<NT, BT, 0, stream>>>(pa, pb, pc, seglen, listd, listz, out, nb);
  } else {
    pre_bin<false><<<nb, 256, 0, stream>>>(
        pos, rgb, opac, quat, scl, w2cr, w2ct, pa, pb, pc, seglen, listd, listz, n);
    render_scan<<<NT, BT, 0, stream>>>(pa, pb, pc, out, n);
  }
}